// Round 1
// baseline (724.817 us; speedup 1.0000x reference)
//
#include <hip/hip_runtime.h>
#include <hip/hip_bf16.h>
#include <math.h>

// Problem constants
#define NN 50000
#define PP 200000
#define LL 6
#define DD 128      // IN_DIM == OUT_DIM
#define HH 4        // heads

// Tiling
#define TM 64       // paths per workgroup
#define NT 512      // threads per workgroup (8 waves)
#define HPAD 132    // fp32 row stride for final-h LDS (bank spread)

typedef __attribute__((ext_vector_type(8))) short short8;   // 8 bf16 (MFMA A/B frag)
typedef __attribute__((ext_vector_type(4))) float f32x4;    // MFMA C/D frag

__device__ __forceinline__ unsigned short f2bf(float v) {
    __hip_bfloat16 h = __float2bfloat16(v);
    return *(unsigned short*)&h;
}
__device__ __forceinline__ float bf2f(unsigned short u) {
    union { unsigned int i; float f; } c; c.i = ((unsigned int)u) << 16; return c.f;
}
__device__ __forceinline__ float fast_rcp(float x) { return __builtin_amdgcn_rcpf(x); }
__device__ __forceinline__ float fast_sigmoid(float x) {
    return fast_rcp(1.f + __expf(-x));
}
__device__ __forceinline__ float fast_tanh(float x) {
    float e = __expf(-2.f * fabsf(x));
    float t = (1.f - e) * fast_rcp(1.f + e);
    return copysignf(t, x);
}

// ---------------------------------------------------------------------------
// Prep: cast W_hh to bf16 (W_ih is consumed directly by the gi GEMM).
// ---------------------------------------------------------------------------
__global__ void prep_w_kernel(const float* __restrict__ w_hh,
                              unsigned short* __restrict__ whb) {
    int i = blockIdx.x * 256 + threadIdx.x;
    if (i < 3 * DD * DD) whb[i] = f2bf(w_hh[i]);
}

// ---------------------------------------------------------------------------
// Counting sort of paths by destination row (= path_list[p][5]).
// ---------------------------------------------------------------------------
__global__ void histo_kernel(const int* __restrict__ path_list,
                             int* __restrict__ cnt) {
    int p = blockIdx.x * 256 + threadIdx.x;
    if (p < PP) atomicAdd(&cnt[path_list[p * LL + (LL - 1)]], 1);
}

__global__ void scan_kernel(const int* __restrict__ cnt,
                            int* __restrict__ offs,
                            int* __restrict__ cursor) {
    __shared__ int ls[256];
    const int t = threadIdx.x;
    const int chunk = (NN + 255) / 256;
    int s = 0;
    for (int j = 0; j < chunk; ++j) {
        int i = t + j * 256;
        if (i < NN) s += cnt[i];
    }
    ls[t] = s; __syncthreads();
    for (int off = 1; off < 256; off <<= 1) {
        int v = (t >= off) ? ls[t - off] : 0;
        __syncthreads();
        ls[t] += v;
        __syncthreads();
    }
    int run = (t == 0) ? 0 : ls[t - 1];
    for (int j = 0; j < chunk; ++j) {
        int i = t + j * 256;
        if (i < NN) { offs[i] = run; cursor[i] = run; run += cnt[i]; }
    }
}

__global__ void scatter_kernel(const int* __restrict__ path_list,
                               int* __restrict__ cursor,
                               int* __restrict__ sorted) {
    int p = blockIdx.x * 256 + threadIdx.x;
    if (p < PP) {
        int row = path_list[p * LL + (LL - 1)];
        int k = atomicAdd(&cursor[row], 1);
        sorted[k] = p;
    }
}

// ---------------------------------------------------------------------------
// gi GEMM: gi[node][c*128+d] = x[node] @ W_ih[c*128+d] + b_ih (+ b_hh for r,z)
// M=50000, N=384, K=128. One WG = 64 rows; wave w owns cols [48w, 48w+48).
// bf16 casts inline (identical RTN rounding to the previous xb/wib path).
// ---------------------------------------------------------------------------
__global__ __launch_bounds__(512, 2)
void gi_gemm_kernel(const float* __restrict__ x,     // [N][128]
                    const float* __restrict__ w_ih,  // [384][128]
                    const float* __restrict__ b_ih,
                    const float* __restrict__ b_hh,
                    float* __restrict__ gi)          // [N][384]
{
    const int tid  = threadIdx.x;
    const int lane = tid & 63;
    const int wave = tid >> 6;
    const int lcol = lane & 15;
    const int quad = lane >> 4;
    const int ko   = quad * 8;
    const int r0   = blockIdx.x * 64;

    short8 B[3][4];
    float bias[3];
    #pragma unroll
    for (int j = 0; j < 3; ++j) {
        int col = wave * 48 + j * 16 + lcol;
        #pragma unroll
        for (int ks = 0; ks < 4; ++ks) {
            const float* src = w_ih + (size_t)col * 128 + ks * 32 + ko;
            short8 b;
            #pragma unroll
            for (int e = 0; e < 8; ++e) b[e] = (short)f2bf(src[e]);
            B[j][ks] = b;
        }
        bias[j] = b_ih[col] + ((col < 256) ? b_hh[col] : 0.f);
    }

    f32x4 acc[3][4];
    #pragma unroll
    for (int j = 0; j < 3; ++j)
        #pragma unroll
        for (int rt = 0; rt < 4; ++rt)
            acc[j][rt] = (f32x4){bias[j], bias[j], bias[j], bias[j]};

    #pragma unroll
    for (int ks = 0; ks < 4; ++ks) {
        #pragma unroll
        for (int rt = 0; rt < 4; ++rt) {
            int row = r0 + rt * 16 + lcol;
            if (row >= NN) row = NN - 1;          // clamp loads, stores guarded
            const float* src = x + (size_t)row * 128 + ks * 32 + ko;
            short8 av;
            #pragma unroll
            for (int e = 0; e < 8; ++e) av[e] = (short)f2bf(src[e]);
            acc[0][rt] = __builtin_amdgcn_mfma_f32_16x16x32_bf16(av, B[0][ks], acc[0][rt], 0, 0, 0);
            acc[1][rt] = __builtin_amdgcn_mfma_f32_16x16x32_bf16(av, B[1][ks], acc[1][rt], 0, 0, 0);
            acc[2][rt] = __builtin_amdgcn_mfma_f32_16x16x32_bf16(av, B[2][ks], acc[2][rt], 0, 0, 0);
        }
    }

    #pragma unroll
    for (int j = 0; j < 3; ++j) {
        int col = wave * 48 + j * 16 + lcol;
        #pragma unroll
        for (int rt = 0; rt < 4; ++rt)
            #pragma unroll
            for (int rr = 0; rr < 4; ++rr) {
                int row = r0 + rt * 16 + quad * 4 + rr;
                if (row < NN) gi[(size_t)row * 384 + col] = acc[j][rt][rr];
            }
    }
}

// ---------------------------------------------------------------------------
// Pass A: h-side-only MFMA GRU.
//  - gi (x-side gates, biases folded) loaded per step from L3-resident table,
//    directly initializing the accumulators -> x-MFMAs, xs staging, xg
//    prefetch and one barrier per step all removed.
//  - hsb double-buffered -> exactly ONE barrier per step, and no global load
//    is ever pending at a barrier (no vmcnt-drain stall).
//  - hs_f (final h, fp32) aliases hsb0+hsb1; a single extra barrier at t=5
//    protects the alias. LDS stays 43.5 KB.
// ---------------------------------------------------------------------------
__global__ __launch_bounds__(NT, 2)
void gru_att_kernel(const float* __restrict__ gi,             // [N][384] fp32
                    const int*   __restrict__ path_list,
                    const unsigned short* __restrict__ whb,   // [384][128] bf16
                    const float* __restrict__ b_hh,
                    const float* __restrict__ a,              // [128][4]
                    float* __restrict__ att_sum,              // [N][4]
                    unsigned short* __restrict__ emb,         // [P][128] bf16
                    float* __restrict__ att_un_g)             // [P][4]
{
    // smem: [0,16384) hsb0 | [16384,32768) hsb1 | hs_f fp32 aliases [0,33792)
    //       [33792,41984) red_s | [41984,43520) nodes_s
    __shared__ __align__(16) unsigned char smem[43520];
    unsigned short* hsb0   = (unsigned short*)smem;
    unsigned short* hsb1   = (unsigned short*)(smem + 16384);
    float*          hs_f   = (float*)smem;                 // alias (final step only)
    float*          red_s  = (float*)(smem + 33792);       // [64][8][4]
    int*            nodes_s= (int*)(smem + 41984);         // [TM*LL]

    const int tid  = threadIdx.x;
    const int lane = tid & 63;
    const int wave = tid >> 6;
    const int lcol = lane & 15;
    const int quad = lane >> 4;
    const int d    = wave * 16 + lcol;
    const int p0   = blockIdx.x * TM;
    const int ko   = quad * 8;

    // persistent h-side B fragments (c=0:r, 1:z, 2:n)
    short8 Bh[3][4];
    #pragma unroll
    for (int c = 0; c < 3; ++c)
        #pragma unroll
        for (int ks = 0; ks < 4; ++ks)
            Bh[c][ks] = *(const short8*)(whb + (size_t)(c * DD + d) * DD + ks * 32 + ko);
    const float bhn = b_hh[d + 256];

    for (int i = tid; i < TM * LL; i += NT) nodes_s[i] = path_list[(size_t)p0 * LL + i];
    for (int i = tid; i < TM * DD / 8; i += NT)
        ((uint4*)hsb0)[i] = make_uint4(0u, 0u, 0u, 0u);

    float hreg[16];
    #pragma unroll
    for (int i = 0; i < 16; ++i) hreg[i] = 0.f;

    __syncthreads();   // nodes_s + hsb0 zero visible

    for (int t = 0; t < LL; ++t) {
        unsigned short* hr = (t & 1) ? hsb1 : hsb0;   // read buffer
        unsigned short* hw = (t & 1) ? hsb0 : hsb1;   // write buffer

        // Issue gi loads early: they resolve from L2/L3 under the MFMA phase.
        // accR/accZ are initialized directly from the loads (bias folded in gi).
        float gin[16];
        f32x4 accR[4], accZ[4], accH[4];
        #pragma unroll
        for (int rt = 0; rt < 4; ++rt)
            #pragma unroll
            for (int r = 0; r < 4; ++r) {
                const int p = rt * 16 + quad * 4 + r;
                const int node = nodes_s[p * LL + t];
                const float* g = gi + (size_t)node * 384 + d;
                accR[rt][r] = g[0];        // ir + b_ih_r + b_hh_r
                accZ[rt][r] = g[128];      // iz + b_ih_z + b_hh_z
                gin[rt * 4 + r] = g[256];  // in + b_ih_n
            }
        #pragma unroll
        for (int rt = 0; rt < 4; ++rt)
            accH[rt] = (f32x4){bhn, bhn, bhn, bhn};

        // MFMA: h-side only (48 MFMAs, 16 ds_read_b128 per wave)
        #pragma unroll
        for (int ks = 0; ks < 4; ++ks) {
            const int kb = ks * 4 + quad;
            #pragma unroll
            for (int rt = 0; rt < 4; ++rt) {
                const int p = rt * 16 + lcol;
                short8 ah = *(const short8*)(hr + p * DD + ((kb ^ lcol) * 8));
                accR[rt] = __builtin_amdgcn_mfma_f32_16x16x32_bf16(ah, Bh[0][ks], accR[rt], 0, 0, 0);
                accZ[rt] = __builtin_amdgcn_mfma_f32_16x16x32_bf16(ah, Bh[1][ks], accZ[rt], 0, 0, 0);
                accH[rt] = __builtin_amdgcn_mfma_f32_16x16x32_bf16(ah, Bh[2][ks], accH[rt], 0, 0, 0);
            }
        }

        if (t == LL - 1) __syncthreads();  // hs_f aliases hsb: all reads done first

        // GRU cell epilogue
        #pragma unroll
        for (int rt = 0; rt < 4; ++rt) {
            #pragma unroll
            for (int r = 0; r < 4; ++r) {
                const int idx = rt * 4 + r;
                const int p   = rt * 16 + quad * 4 + r;
                float rg = fast_sigmoid(accR[rt][r]);
                float zg = fast_sigmoid(accZ[rt][r]);
                float ng = fast_tanh(gin[idx] + rg * accH[rt][r]);  // accH = hn + b_hh_n
                float hnew = fmaf(zg, hreg[idx] - ng, ng);
                hreg[idx] = hnew;
                if (t < LL - 1) {
                    hw[p * DD + (((d >> 3) ^ (p & 15)) * 8) + (d & 7)] = f2bf(hnew);
                } else {
                    hs_f[p * HPAD + d] = hnew;   // fp32, aliases dead hsb
                }
            }
        }
        __syncthreads();   // hw complete (and, at t=5, hs_f complete)
    }

    // attention logits + emit bf16 path embedding
    {
        int pi = tid >> 3, tt = tid & 7;
        float s0 = 0.f, s1 = 0.f, s2 = 0.f, s3 = 0.f;
        unsigned short pack[16];
        #pragma unroll
        for (int j = 0; j < 16; ++j) {
            int dd2 = tt * 16 + j;
            float hv = hs_f[pi * HPAD + dd2];
            pack[j] = f2bf(hv);
            float4 av = *(const float4*)(a + dd2 * 4);
            s0 += hv * av.x; s1 += hv * av.y; s2 += hv * av.z; s3 += hv * av.w;
        }
        uint4* dst = (uint4*)(emb + (size_t)(p0 + pi) * DD + tt * 16);
        dst[0] = *(uint4*)&pack[0];
        dst[1] = *(uint4*)&pack[8];
        float* rp = red_s + (pi * 8 + tt) * 4;
        rp[0] = s0; rp[1] = s1; rp[2] = s2; rp[3] = s3;
    }
    __syncthreads();
    if (tid < TM) {
        int pi = tid;
        int row = nodes_s[pi * LL + (LL - 1)];
        float4 e4;
        #pragma unroll
        for (int h = 0; h < HH; ++h) {
            float s = 0.f;
            #pragma unroll
            for (int tt = 0; tt < 8; ++tt) s += red_s[(pi * 8 + tt) * 4 + h];
            float lv = (s > 0.f) ? s : 0.2f * s;
            float e  = __expf(lv);
            ((float*)&e4)[h] = e;
            atomicAdd(&att_sum[row * HH + h], e);
        }
        *(float4*)(att_un_g + (size_t)(p0 + pi) * HH) = e4;
    }
}

// ---------------------------------------------------------------------------
// Pass B: per-node aggregation over its sorted paths. Atomic-free.
// ---------------------------------------------------------------------------
__global__ __launch_bounds__(256)
void agg_kernel(const unsigned short* __restrict__ emb,   // [P][128] bf16
                const float* __restrict__ att_un,         // [P][4]
                const float* __restrict__ att_sum,        // [N][4]
                const int* __restrict__ offs,
                const int* __restrict__ cnt,
                const int* __restrict__ sorted,
                float* __restrict__ out)                  // [N][512]
{
    int node = blockIdx.x * 2 + (threadIdx.x >> 7);
    int d    = threadIdx.x & 127;
    if (node >= NN) return;
    int start = offs[node];
    int len   = cnt[node];
    float a0 = 0.f, a1 = 0.f, a2 = 0.f, a3 = 0.f;
    for (int i = 0; i < len; ++i) {
        int p = sorted[start + i];
        float4 at = *(const float4*)(att_un + (size_t)p * 4);
        float ev = bf2f(emb[(size_t)p * DD + d]);
        a0 = fmaf(at.x, ev, a0);
        a1 = fmaf(at.y, ev, a1);
        a2 = fmaf(at.z, ev, a2);
        a3 = fmaf(at.w, ev, a3);
    }
    float4 s = *(const float4*)(att_sum + (size_t)node * 4);
    float* o = out + (size_t)node * 512 + d;
    o[0]   = (s.x > 0.f) ? a0 / s.x : 0.f;
    o[128] = (s.y > 0.f) ? a1 / s.y : 0.f;
    o[256] = (s.z > 0.f) ? a2 / s.z : 0.f;
    o[384] = (s.w > 0.f) ? a3 / s.w : 0.f;
}

extern "C" void kernel_launch(void* const* d_in, const int* in_sizes, int n_in,
                              void* d_out, int out_size, void* d_ws, size_t ws_size,
                              hipStream_t stream) {
    const float* x         = (const float*)d_in[0];
    const int*   path_list = (const int*)  d_in[1];
    const float* w_ih      = (const float*)d_in[2];
    const float* w_hh      = (const float*)d_in[3];
    const float* b_ih      = (const float*)d_in[4];
    const float* b_hh      = (const float*)d_in[5];
    const float* a         = (const float*)d_in[6];
    float* out = (float*)d_out;

    // workspace layout (all 16B-multiple sizes), total ~133.5 MB
    char* w = (char*)d_ws;
    float*          att_sum = (float*)w;                 w += 800000;       // N*4 f32
    int*            cnt     = (int*)w;                   w += 200000;       // N
    int*            offs    = (int*)w;                   w += 200000;       // N
    int*            cursor  = (int*)w;                   w += 200000;       // N
    int*            sorted  = (int*)w;                   w += 800000;       // P
    float*          att_un  = (float*)w;                 w += 3200000;      // P*4 f32
    float*          gi      = (float*)w;                 w += 76800000;     // N*384 f32
    unsigned short* whb     = (unsigned short*)w;        w += 98304;        // 384*128 bf16
    unsigned short* emb     = (unsigned short*)w;        w += 51200000;     // P*128 bf16

    hipMemsetAsync(att_sum, 0, 800000, stream);
    hipMemsetAsync(cnt, 0, 200000, stream);

    prep_w_kernel<<<(3 * DD * DD + 255) / 256, 256, 0, stream>>>(w_hh, whb);

    histo_kernel<<<(PP + 255) / 256, 256, 0, stream>>>(path_list, cnt);
    scan_kernel<<<1, 256, 0, stream>>>(cnt, offs, cursor);
    scatter_kernel<<<(PP + 255) / 256, 256, 0, stream>>>(path_list, cursor, sorted);

    gi_gemm_kernel<<<(NN + 63) / 64, 512, 0, stream>>>(x, w_ih, b_ih, b_hh, gi);

    gru_att_kernel<<<PP / TM, NT, 0, stream>>>(gi, path_list, whb,
                                               b_hh, a, att_sum, emb, att_un);

    agg_kernel<<<(NN + 1) / 2, 256, 0, stream>>>(emb, att_un, att_sum,
                                                 offs, cnt, sorted, out);
}